// Round 1
// baseline (5855.821 us; speedup 1.0000x reference)
//
#include <hip/hip_runtime.h>
#include <hip/hip_bf16.h>
#include <math.h>

// Problem constants (MambaStack reference)
#define DEPTH   2
#define DM      768      // d_model
#define DS      64       // d_state
#define DC      4        // d_conv
#define DI      1536     // d_inner
#define DTR     48       // dt_rank
#define BATCH   4
#define SEQ     2048
#define MROWS   (BATCH*SEQ)          // 8192
#define XDC     (DTR + 2*DS)         // 176 (xdbl cols)

__device__ __forceinline__ float silu_fast(float x) {
    return x / (1.f + __expf(-x));
}
__device__ __forceinline__ float softplus_acc(float x) {
    return x > 20.f ? x : log1pf(expf(x));
}

// C[M,N] = A[M,K] (row-major, ldA) @ W[N,K]^T  (W row-major, ld = K)
// EPI: 0 = none, 1 = softplus(x + bias[col])
// Tiles: 128x128x8, 256 threads, 8x8 per thread.
template<int EPI>
__global__ __launch_bounds__(256, 2) void gemm_nt(
    const float* __restrict__ A, int ldA,
    const float* __restrict__ W,
    const float* __restrict__ bias,
    float* __restrict__ C, int ldC,
    int N, int K)
{
    __shared__ float As[8][132];
    __shared__ float Bs[8][132];
    const int tid = threadIdx.x;
    const int bm0 = blockIdx.y * 128;
    const int bn0 = blockIdx.x * 128;
    const int tx = tid & 15;          // col group
    const int ty = tid >> 4;          // row group
    const int lrow = tid >> 1;        // 0..127  (staging row)
    const int lk4  = (tid & 1) * 4;   // 0 or 4  (staging k quad)

    float acc[8][8];
#pragma unroll
    for (int i = 0; i < 8; i++)
#pragma unroll
        for (int j = 0; j < 8; j++) acc[i][j] = 0.f;

    for (int k0 = 0; k0 < K; k0 += 8) {
        const float4 av = *(const float4*)(A + (size_t)(bm0 + lrow) * ldA + (k0 + lk4));
        float4 wv;
        const int wrow = bn0 + lrow;
        if (wrow < N) wv = *(const float4*)(W + (size_t)wrow * K + (k0 + lk4));
        else          wv = make_float4(0.f, 0.f, 0.f, 0.f);
        __syncthreads();
        As[lk4 + 0][lrow] = av.x; As[lk4 + 1][lrow] = av.y;
        As[lk4 + 2][lrow] = av.z; As[lk4 + 3][lrow] = av.w;
        Bs[lk4 + 0][lrow] = wv.x; Bs[lk4 + 1][lrow] = wv.y;
        Bs[lk4 + 2][lrow] = wv.z; Bs[lk4 + 3][lrow] = wv.w;
        __syncthreads();
#pragma unroll
        for (int kk = 0; kk < 8; kk++) {
            const float4 a0 = *(const float4*)&As[kk][ty * 8];
            const float4 a1 = *(const float4*)&As[kk][ty * 8 + 4];
            const float4 b0 = *(const float4*)&Bs[kk][tx * 8];
            const float4 b1 = *(const float4*)&Bs[kk][tx * 8 + 4];
            const float ar[8] = {a0.x, a0.y, a0.z, a0.w, a1.x, a1.y, a1.z, a1.w};
            const float br[8] = {b0.x, b0.y, b0.z, b0.w, b1.x, b1.y, b1.z, b1.w};
#pragma unroll
            for (int i = 0; i < 8; i++)
#pragma unroll
                for (int j = 0; j < 8; j++)
                    acc[i][j] = fmaf(ar[i], br[j], acc[i][j]);
        }
    }

#pragma unroll
    for (int i = 0; i < 8; i++) {
        const int row = bm0 + ty * 8 + i;   // always < M (M multiple of 128)
#pragma unroll
        for (int j4 = 0; j4 < 8; j4 += 4) {
            const int col = bn0 + tx * 8 + j4;
            if (col + 3 < N) {
                float4 v = make_float4(acc[i][j4], acc[i][j4 + 1], acc[i][j4 + 2], acc[i][j4 + 3]);
                if (EPI == 1) {
                    v.x = softplus_acc(v.x + bias[col + 0]);
                    v.y = softplus_acc(v.y + bias[col + 1]);
                    v.z = softplus_acc(v.z + bias[col + 2]);
                    v.w = softplus_acc(v.w + bias[col + 3]);
                }
                *(float4*)(C + (size_t)row * ldC + col) = v;
            }
        }
    }
}

// Depthwise causal conv (K=4) + SiLU.  Reads xpart = xz[:, 0:DI], writes xc.
__global__ __launch_bounds__(256) void conv_silu_kernel(
    const float* __restrict__ xz, const float* __restrict__ cw,
    const float* __restrict__ cb, float* __restrict__ xc)
{
    const int idx = blockIdx.x * 256 + threadIdx.x;   // over MROWS*DI
    const int d   = idx % DI;
    const int row = idx / DI;
    const int l   = row % SEQ;
    const float4 w = ((const float4*)cw)[d];          // conv_w[d, 0:4]
    const float* col = xz + (size_t)row * (2 * DI) + d;
    float acc = cb[d];
    if (l >= 3) {
        acc = fmaf(col[-3 * 2 * DI], w.x, acc);
        acc = fmaf(col[-2 * 2 * DI], w.y, acc);
        acc = fmaf(col[-1 * 2 * DI], w.z, acc);
        acc = fmaf(col[0],           w.w, acc);
    } else {
        const float wk[4] = {w.x, w.y, w.z, w.w};
#pragma unroll
        for (int k = 0; k < 4; k++) {
            const int l2 = l - 3 + k;
            if (l2 >= 0) acc = fmaf(col[(k - 3) * 2 * DI], wk[k], acc);
        }
    }
    xc[idx] = silu_fast(acc);
}

// Selective scan. One wave per (b, d) pair; lane = state index n.
// dt lives in xz[:, 0:DI] (written by the dt GEMM), z in xz[:, DI:2*DI].
// u = xc (conv output); y overwrites xc in place:
//   y = (scan_y + D*u) * silu(z)
__global__ __launch_bounds__(256) void scan_kernel(
    const float* __restrict__ xz, float* __restrict__ xc,
    const float* __restrict__ xdbl,
    const float* __restrict__ A_log, const float* __restrict__ Dskip)
{
    const int wv   = __builtin_amdgcn_readfirstlane((int)threadIdx.x) >> 6;
    const int pair = blockIdx.x * 4 + wv;         // 0 .. BATCH*DI-1
    const int b    = pair / DI;
    const int d    = pair - b * DI;
    const int lane = threadIdx.x & 63;

    // A = -exp(A_log); pre-scale by log2(e) so per-step exp is a single v_exp.
    const float An = -expf(A_log[d * DS + lane]) * 1.44269504088896f;
    const float Dd = Dskip[d];

    const float* xzr = xz   + (size_t)b * SEQ * (2 * DI);
    float*       xcr = xc   + (size_t)b * SEQ * DI;
    const float* xdr = xdbl + (size_t)b * SEQ * XDC;

    float h = 0.f;
    for (int t = 0; t < SEQ; t++) {
        const float dtv = xzr[t * (2 * DI) + d];           // uniform (scalar load)
        const float zv  = xzr[t * (2 * DI) + DI + d];      // uniform
        const float uv  = xcr[t * DI + d];                 // uniform
        const float Bv  = xdr[t * XDC + DTR + lane];       // coalesced
        const float Cv  = xdr[t * XDC + DTR + DS + lane];  // coalesced
        const float dA  = exp2f(dtv * An);
        h = fmaf(dA, h, dtv * uv * Bv);
        float p = h * Cv;
#pragma unroll
        for (int m = 1; m < 64; m <<= 1) p += __shfl_xor(p, m, 64);
        if (lane == 0) {
            float yv = p + Dd * uv;
            yv *= silu_fast(zv);
            xcr[t * DI + d] = yv;
        }
    }
}

extern "C" void kernel_launch(void* const* d_in, const int* in_sizes, int n_in,
                              void* d_out, int out_size, void* d_ws, size_t ws_size,
                              hipStream_t stream) {
    (void)in_sizes; (void)n_in; (void)out_size; (void)ws_size;
    const float* x    = (const float*)d_in[0];
    const float* Wi   = (const float*)d_in[1];
    const float* cw   = (const float*)d_in[2];
    const float* cb   = (const float*)d_in[3];
    const float* Wx   = (const float*)d_in[4];
    const float* Wdt  = (const float*)d_in[5];
    const float* bdt  = (const float*)d_in[6];
    const float* Alog = (const float*)d_in[7];
    const float* Dsk  = (const float*)d_in[8];
    const float* Wo   = (const float*)d_in[9];
    float* out = (float*)d_out;

    // Workspace layout (fp32), ~182 MB total:
    float* xz    = (float*)d_ws;                          // [MROWS, 3072]
    float* xc    = xz    + (size_t)MROWS * (2 * DI);      // [MROWS, 1536]
    float* xdbl  = xc    + (size_t)MROWS * DI;            // [MROWS, 176]
    float* xnext = xdbl  + (size_t)MROWS * XDC;           // [MROWS, 768]

    const float* src = x;
    for (int i = 0; i < DEPTH; i++) {
        const float* Wi_l   = Wi   + (size_t)i * 2 * DI * DM;
        const float* cw_l   = cw   + (size_t)i * DI * DC;
        const float* cb_l   = cb   + (size_t)i * DI;
        const float* Wx_l   = Wx   + (size_t)i * XDC * DI;
        const float* Wdt_l  = Wdt  + (size_t)i * DI * DTR;
        const float* bdt_l  = bdt  + (size_t)i * DI;
        const float* Alog_l = Alog + (size_t)i * DI * DS;
        const float* Dsk_l  = Dsk  + (size_t)i * DI;
        const float* Wo_l   = Wo   + (size_t)i * DM * DI;
        float* dst = (i == DEPTH - 1) ? out : xnext;

        // 1. xz = src @ Wi^T                       [8192, 3072]
        gemm_nt<0><<<dim3(2 * DI / 128, MROWS / 128), 256, 0, stream>>>(
            src, DM, Wi_l, nullptr, xz, 2 * DI, 2 * DI, DM);
        // 2. xc = silu(causal_conv(xz[:, :DI]))    [8192, 1536]
        conv_silu_kernel<<<(size_t)MROWS * DI / 256, 256, 0, stream>>>(xz, cw_l, cb_l, xc);
        // 3. xdbl = xc @ Wx^T                      [8192, 176]
        gemm_nt<0><<<dim3((XDC + 127) / 128, MROWS / 128), 256, 0, stream>>>(
            xc, DI, Wx_l, nullptr, xdbl, XDC, XDC, DI);
        // 4. dt = softplus(xdbl[:, :48] @ Wdt^T + bdt) -> xz[:, 0:DI] (xpart is dead there)
        gemm_nt<1><<<dim3(DI / 128, MROWS / 128), 256, 0, stream>>>(
            xdbl, XDC, Wdt_l, bdt_l, xz, 2 * DI, DI, DTR);
        // 5. selective scan; y (gated) overwrites xc in place
        scan_kernel<<<(BATCH * DI) / 4, 256, 0, stream>>>(xz, xc, xdbl, Alog_l, Dsk_l);
        // 6. dst = y @ Wo^T                        [8192, 768]
        gemm_nt<0><<<dim3(DM / 128, MROWS / 128), 256, 0, stream>>>(
            xc, DI, Wo_l, nullptr, dst, DM, DM, DI);

        src = dst;
    }
}

// Round 2
// 5383.893 us; speedup vs baseline: 1.0877x; 1.0877x over previous
//
#include <hip/hip_runtime.h>
#include <hip/hip_bf16.h>
#include <math.h>

// Problem constants (MambaStack reference)
#define DEPTH   2
#define DM      768      // d_model
#define DS      64       // d_state
#define DC      4        // d_conv
#define DI      1536     // d_inner
#define DTR     48       // dt_rank
#define BATCH   4
#define SEQ     2048
#define MROWS   (BATCH*SEQ)          // 8192
#define XDC     (DTR + 2*DS)         // 176 (xdbl cols)
#define NC      8                    // scan chunks
#define TCH     (SEQ/NC)             // 256 timesteps per chunk

__device__ __forceinline__ float silu_fast(float x) {
    return x / (1.f + __expf(-x));
}
__device__ __forceinline__ float softplus_acc(float x) {
    return x > 20.f ? x : log1pf(expf(x));
}

// C[M,N] = A[M,K] (row-major, ldA) @ W[N,K]^T  (W row-major, ld = K)
// EPI: 0 = none, 1 = softplus(x + bias[col])
// Tiles: 128x128x8, 256 threads, 8x8 per thread.
template<int EPI>
__global__ __launch_bounds__(256, 2) void gemm_nt(
    const float* __restrict__ A, int ldA,
    const float* __restrict__ W,
    const float* __restrict__ bias,
    float* __restrict__ C, int ldC,
    int N, int K)
{
    __shared__ float As[8][132];
    __shared__ float Bs[8][132];
    const int tid = threadIdx.x;
    const int bm0 = blockIdx.y * 128;
    const int bn0 = blockIdx.x * 128;
    const int tx = tid & 15;          // col group
    const int ty = tid >> 4;          // row group
    const int lrow = tid >> 1;        // 0..127  (staging row)
    const int lk4  = (tid & 1) * 4;   // 0 or 4  (staging k quad)

    float acc[8][8];
#pragma unroll
    for (int i = 0; i < 8; i++)
#pragma unroll
        for (int j = 0; j < 8; j++) acc[i][j] = 0.f;

    for (int k0 = 0; k0 < K; k0 += 8) {
        const float4 av = *(const float4*)(A + (size_t)(bm0 + lrow) * ldA + (k0 + lk4));
        float4 wv;
        const int wrow = bn0 + lrow;
        if (wrow < N) wv = *(const float4*)(W + (size_t)wrow * K + (k0 + lk4));
        else          wv = make_float4(0.f, 0.f, 0.f, 0.f);
        __syncthreads();
        As[lk4 + 0][lrow] = av.x; As[lk4 + 1][lrow] = av.y;
        As[lk4 + 2][lrow] = av.z; As[lk4 + 3][lrow] = av.w;
        Bs[lk4 + 0][lrow] = wv.x; Bs[lk4 + 1][lrow] = wv.y;
        Bs[lk4 + 2][lrow] = wv.z; Bs[lk4 + 3][lrow] = wv.w;
        __syncthreads();
#pragma unroll
        for (int kk = 0; kk < 8; kk++) {
            const float4 a0 = *(const float4*)&As[kk][ty * 8];
            const float4 a1 = *(const float4*)&As[kk][ty * 8 + 4];
            const float4 b0 = *(const float4*)&Bs[kk][tx * 8];
            const float4 b1 = *(const float4*)&Bs[kk][tx * 8 + 4];
            const float ar[8] = {a0.x, a0.y, a0.z, a0.w, a1.x, a1.y, a1.z, a1.w};
            const float br[8] = {b0.x, b0.y, b0.z, b0.w, b1.x, b1.y, b1.z, b1.w};
#pragma unroll
            for (int i = 0; i < 8; i++)
#pragma unroll
                for (int j = 0; j < 8; j++)
                    acc[i][j] = fmaf(ar[i], br[j], acc[i][j]);
        }
    }

#pragma unroll
    for (int i = 0; i < 8; i++) {
        const int row = bm0 + ty * 8 + i;   // always < M (M multiple of 128)
#pragma unroll
        for (int j4 = 0; j4 < 8; j4 += 4) {
            const int col = bn0 + tx * 8 + j4;
            if (col + 3 < N) {
                float4 v = make_float4(acc[i][j4], acc[i][j4 + 1], acc[i][j4 + 2], acc[i][j4 + 3]);
                if (EPI == 1) {
                    v.x = softplus_acc(v.x + bias[col + 0]);
                    v.y = softplus_acc(v.y + bias[col + 1]);
                    v.z = softplus_acc(v.z + bias[col + 2]);
                    v.w = softplus_acc(v.w + bias[col + 3]);
                }
                *(float4*)(C + (size_t)row * ldC + col) = v;
            }
        }
    }
}

// Depthwise causal conv (K=4) + SiLU.  Reads xpart = xz[:, 0:DI], writes xc.
__global__ __launch_bounds__(256) void conv_silu_kernel(
    const float* __restrict__ xz, const float* __restrict__ cw,
    const float* __restrict__ cb, float* __restrict__ xc)
{
    const int idx = blockIdx.x * 256 + threadIdx.x;   // over MROWS*DI
    const int d   = idx % DI;
    const int row = idx / DI;
    const int l   = row % SEQ;
    const float4 w = ((const float4*)cw)[d];          // conv_w[d, 0:4]
    const float* col = xz + (size_t)row * (2 * DI) + d;
    float acc = cb[d];
    if (l >= 3) {
        acc = fmaf(col[-3 * 2 * DI], w.x, acc);
        acc = fmaf(col[-2 * 2 * DI], w.y, acc);
        acc = fmaf(col[-1 * 2 * DI], w.z, acc);
        acc = fmaf(col[0],           w.w, acc);
    } else {
        const float wk[4] = {w.x, w.y, w.z, w.w};
#pragma unroll
        for (int k = 0; k < 4; k++) {
            const int l2 = l - 3 + k;
            if (l2 >= 0) acc = fmaf(col[(k - 3) * 2 * DI], wk[k], acc);
        }
    }
    xc[idx] = silu_fast(acc);
}

// ---------------- Chunked selective scan (3 phases) ----------------
// The recurrence h[t] = dA[t]*h[t-1] + dt[t]*B[t]*u[t] is linear-diagonal, so
// chunk c's effect is h_end_c = P_c * h_in_c + h_local_c with
// P_c = prod(dA) = exp2(An * sum(dt)).  Phase1 computes h_local/P per chunk
// (49152 waves -> 48 waves/SIMD, latency fully hidden), phase2 is a tiny
// sequential fix-up per (b,d), phase3 resumes the exact scan from h_in.

// Phase 1: per (b,d,chunk) wave, lane = state n.
__global__ __launch_bounds__(256) void scan_phase1(
    const float* __restrict__ xz, const float* __restrict__ xc,
    const float* __restrict__ xdbl, const float* __restrict__ A_log,
    float* __restrict__ hend, float* __restrict__ prodA)
{
    const int wid  = (blockIdx.x * 256 + threadIdx.x) >> 6;  // (b*DI+d)*NC + c
    const int lane = threadIdx.x & 63;
    const int c  = wid & (NC - 1);
    const int bd = wid / NC;
    const int b  = bd / DI;
    const int d  = bd - b * DI;

    const float An = -expf(A_log[d * DS + lane]) * 1.44269504088896f;
    const size_t r0 = (size_t)b * SEQ + (size_t)c * TCH;
    const float* xzr = xz   + r0 * (2 * DI) + d;
    const float* xcr = xc   + r0 * DI + d;
    const float* xdr = xdbl + r0 * XDC + DTR + lane;

    float h = 0.f, sdt = 0.f;
    for (int t = 0; t < TCH; t++) {
        const float dtv = xzr[t * (2 * DI)];    // wave-uniform
        const float uv  = xcr[t * DI];          // wave-uniform
        const float Bv  = xdr[t * XDC];         // coalesced
        const float dA  = exp2f(dtv * An);
        h = fmaf(dA, h, dtv * uv * Bv);
        sdt += dtv;
    }
    hend [(size_t)wid * DS + lane] = h;
    prodA[(size_t)wid * DS + lane] = exp2f(An * sdt);
}

// Phase 2: per (b,d) wave, serial over chunks; writes h_in into prodA in place.
__global__ __launch_bounds__(256) void scan_phase2(
    float* __restrict__ hend, float* __restrict__ prodA)
{
    const int bd   = (blockIdx.x * 256 + threadIdx.x) >> 6;  // b*DI + d
    const int lane = threadIdx.x & 63;
    float h = 0.f;
#pragma unroll
    for (int c = 0; c < NC; c++) {
        const size_t off = ((size_t)bd * NC + c) * DS + lane;
        const float pA = prodA[off];
        const float he = hend[off];
        prodA[off] = h;            // h_in for chunk c (read-before-write)
        h = fmaf(pA, h, he);
    }
}

// Phase 3: resumed scan + y = (C.h + D*u) * silu(z), overwrites xc in place.
__global__ __launch_bounds__(256) void scan_phase3(
    const float* __restrict__ xz, float* __restrict__ xc,
    const float* __restrict__ xdbl, const float* __restrict__ A_log,
    const float* __restrict__ Dskip, const float* __restrict__ hin)
{
    const int wid  = (blockIdx.x * 256 + threadIdx.x) >> 6;  // (b*DI+d)*NC + c
    const int lane = threadIdx.x & 63;
    const int c  = wid & (NC - 1);
    const int bd = wid / NC;
    const int b  = bd / DI;
    const int d  = bd - b * DI;

    const float An = -expf(A_log[d * DS + lane]) * 1.44269504088896f;
    const float Dd = Dskip[d];
    const size_t r0 = (size_t)b * SEQ + (size_t)c * TCH;
    const float* xzr = xz   + r0 * (2 * DI) + d;
    float*       xcr = xc   + r0 * DI + d;
    const float* xdr = xdbl + r0 * XDC + DTR + lane;

    float h = hin[(size_t)wid * DS + lane];
    for (int t = 0; t < TCH; t++) {
        const float dtv = xzr[t * (2 * DI)];        // wave-uniform
        const float zv  = xzr[t * (2 * DI) + DI];   // wave-uniform
        const float uv  = xcr[t * DI];              // wave-uniform
        const float Bv  = xdr[t * XDC];             // coalesced
        const float Cv  = xdr[t * XDC + DS];        // coalesced
        const float dA  = exp2f(dtv * An);
        h = fmaf(dA, h, dtv * uv * Bv);
        float p = h * Cv;
#pragma unroll
        for (int m = 1; m < 64; m <<= 1) p += __shfl_xor(p, m, 64);
        if (lane == 0) {
            float yv = p + Dd * uv;
            yv *= silu_fast(zv);
            xcr[t * DI] = yv;
        }
    }
}

extern "C" void kernel_launch(void* const* d_in, const int* in_sizes, int n_in,
                              void* d_out, int out_size, void* d_ws, size_t ws_size,
                              hipStream_t stream) {
    (void)in_sizes; (void)n_in; (void)out_size; (void)ws_size;
    const float* x    = (const float*)d_in[0];
    const float* Wi   = (const float*)d_in[1];
    const float* cw   = (const float*)d_in[2];
    const float* cb   = (const float*)d_in[3];
    const float* Wx   = (const float*)d_in[4];
    const float* Wdt  = (const float*)d_in[5];
    const float* bdt  = (const float*)d_in[6];
    const float* Alog = (const float*)d_in[7];
    const float* Dsk  = (const float*)d_in[8];
    const float* Wo   = (const float*)d_in[9];
    float* out = (float*)d_out;

    // Workspace layout (fp32), ~207 MB total:
    float* xz    = (float*)d_ws;                          // [MROWS, 3072]
    float* xc    = xz    + (size_t)MROWS * (2 * DI);      // [MROWS, 1536]
    float* xdbl  = xc    + (size_t)MROWS * DI;            // [MROWS, 176]
    float* xnext = xdbl  + (size_t)MROWS * XDC;           // [MROWS, 768]
    float* hend  = xnext + (size_t)MROWS * DM;            // [B*DI*NC, DS]
    float* prodA = hend  + (size_t)BATCH * DI * NC * DS;  // [B*DI*NC, DS]

    const float* src = x;
    for (int i = 0; i < DEPTH; i++) {
        const float* Wi_l   = Wi   + (size_t)i * 2 * DI * DM;
        const float* cw_l   = cw   + (size_t)i * DI * DC;
        const float* cb_l   = cb   + (size_t)i * DI;
        const float* Wx_l   = Wx   + (size_t)i * XDC * DI;
        const float* Wdt_l  = Wdt  + (size_t)i * DI * DTR;
        const float* bdt_l  = bdt  + (size_t)i * DI;
        const float* Alog_l = Alog + (size_t)i * DI * DS;
        const float* Dsk_l  = Dsk  + (size_t)i * DI;
        const float* Wo_l   = Wo   + (size_t)i * DM * DI;
        float* dst = (i == DEPTH - 1) ? out : xnext;

        // 1. xz = src @ Wi^T                       [8192, 3072]
        gemm_nt<0><<<dim3(2 * DI / 128, MROWS / 128), 256, 0, stream>>>(
            src, DM, Wi_l, nullptr, xz, 2 * DI, 2 * DI, DM);
        // 2. xc = silu(causal_conv(xz[:, :DI]))    [8192, 1536]
        conv_silu_kernel<<<(size_t)MROWS * DI / 256, 256, 0, stream>>>(xz, cw_l, cb_l, xc);
        // 3. xdbl = xc @ Wx^T                      [8192, 176]
        gemm_nt<0><<<dim3((XDC + 127) / 128, MROWS / 128), 256, 0, stream>>>(
            xc, DI, Wx_l, nullptr, xdbl, XDC, XDC, DI);
        // 4. dt = softplus(xdbl[:, :48] @ Wdt^T + bdt) -> xz[:, 0:DI] (xpart dead there)
        gemm_nt<1><<<dim3(DI / 128, MROWS / 128), 256, 0, stream>>>(
            xdbl, XDC, Wdt_l, bdt_l, xz, 2 * DI, DI, DTR);
        // 5. chunked selective scan; gated y overwrites xc in place
        scan_phase1<<<(BATCH * DI * NC) / 4, 256, 0, stream>>>(
            xz, xc, xdbl, Alog_l, hend, prodA);
        scan_phase2<<<(BATCH * DI) / 4, 256, 0, stream>>>(hend, prodA);
        scan_phase3<<<(BATCH * DI * NC) / 4, 256, 0, stream>>>(
            xz, xc, xdbl, Alog_l, Dsk_l, prodA);
        // 6. dst = y @ Wo^T                        [8192, 768]
        gemm_nt<0><<<dim3(DM / 128, MROWS / 128), 256, 0, stream>>>(
            xc, DI, Wo_l, nullptr, dst, DM, DM, DI);

        src = dst;
    }
}

// Round 3
// 5197.011 us; speedup vs baseline: 1.1268x; 1.0360x over previous
//
#include <hip/hip_runtime.h>
#include <hip/hip_bf16.h>
#include <math.h>

// Problem constants (MambaStack reference)
#define DEPTH   2
#define DM      768      // d_model
#define DS      64       // d_state
#define DC      4        // d_conv
#define DI      1536     // d_inner
#define DTR     48       // dt_rank
#define BATCH   4
#define SEQ     2048
#define MROWS   (BATCH*SEQ)          // 8192
#define XDC     (DTR + 2*DS)         // 176 (xdbl cols)
#define NC      8                    // scan chunks
#define TCH     (SEQ/NC)             // 256 timesteps per chunk
#define LOG2E   1.44269504088896f

__device__ __forceinline__ float silu_fast(float x) {
    return x / (1.f + __expf(-x));
}
__device__ __forceinline__ float softplus_acc(float x) {
    return x > 20.f ? x : log1pf(expf(x));
}

// C[M,N] = A[M,K] (row-major, ldA) @ W[N,K]^T  (W row-major, ld = K)
// EPI: 0 = none, 1 = softplus(x + bias[col])
template<int EPI>
__global__ __launch_bounds__(256, 2) void gemm_nt(
    const float* __restrict__ A, int ldA,
    const float* __restrict__ W,
    const float* __restrict__ bias,
    float* __restrict__ C, int ldC,
    int N, int K)
{
    __shared__ float As[8][132];
    __shared__ float Bs[8][132];
    const int tid = threadIdx.x;
    const int bm0 = blockIdx.y * 128;
    const int bn0 = blockIdx.x * 128;
    const int tx = tid & 15;
    const int ty = tid >> 4;
    const int lrow = tid >> 1;
    const int lk4  = (tid & 1) * 4;

    float acc[8][8];
#pragma unroll
    for (int i = 0; i < 8; i++)
#pragma unroll
        for (int j = 0; j < 8; j++) acc[i][j] = 0.f;

    for (int k0 = 0; k0 < K; k0 += 8) {
        const float4 av = *(const float4*)(A + (size_t)(bm0 + lrow) * ldA + (k0 + lk4));
        float4 wv;
        const int wrow = bn0 + lrow;
        if (wrow < N) wv = *(const float4*)(W + (size_t)wrow * K + (k0 + lk4));
        else          wv = make_float4(0.f, 0.f, 0.f, 0.f);
        __syncthreads();
        As[lk4 + 0][lrow] = av.x; As[lk4 + 1][lrow] = av.y;
        As[lk4 + 2][lrow] = av.z; As[lk4 + 3][lrow] = av.w;
        Bs[lk4 + 0][lrow] = wv.x; Bs[lk4 + 1][lrow] = wv.y;
        Bs[lk4 + 2][lrow] = wv.z; Bs[lk4 + 3][lrow] = wv.w;
        __syncthreads();
#pragma unroll
        for (int kk = 0; kk < 8; kk++) {
            const float4 a0 = *(const float4*)&As[kk][ty * 8];
            const float4 a1 = *(const float4*)&As[kk][ty * 8 + 4];
            const float4 b0 = *(const float4*)&Bs[kk][tx * 8];
            const float4 b1 = *(const float4*)&Bs[kk][tx * 8 + 4];
            const float ar[8] = {a0.x, a0.y, a0.z, a0.w, a1.x, a1.y, a1.z, a1.w};
            const float br[8] = {b0.x, b0.y, b0.z, b0.w, b1.x, b1.y, b1.z, b1.w};
#pragma unroll
            for (int i = 0; i < 8; i++)
#pragma unroll
                for (int j = 0; j < 8; j++)
                    acc[i][j] = fmaf(ar[i], br[j], acc[i][j]);
        }
    }

#pragma unroll
    for (int i = 0; i < 8; i++) {
        const int row = bm0 + ty * 8 + i;
#pragma unroll
        for (int j4 = 0; j4 < 8; j4 += 4) {
            const int col = bn0 + tx * 8 + j4;
            if (col + 3 < N) {
                float4 v = make_float4(acc[i][j4], acc[i][j4 + 1], acc[i][j4 + 2], acc[i][j4 + 3]);
                if (EPI == 1) {
                    v.x = softplus_acc(v.x + bias[col + 0]);
                    v.y = softplus_acc(v.y + bias[col + 1]);
                    v.z = softplus_acc(v.z + bias[col + 2]);
                    v.w = softplus_acc(v.w + bias[col + 3]);
                }
                *(float4*)(C + (size_t)row * ldC + col) = v;
            }
        }
    }
}

// Fused depthwise causal conv (K=4) + SiLU, writing BOTH layouts:
//   xc [row, d] row-major (for x_proj GEMM) and uT [b][d][t] (for scan).
// Tile: 64 t x 64 d per block, 256 threads.
__global__ __launch_bounds__(256) void conv_silu_trans(
    const float* __restrict__ xz, const float* __restrict__ cw,
    const float* __restrict__ cb, float* __restrict__ xc,
    float* __restrict__ uT)
{
    __shared__ float tin[67][65];   // [t(-3..63)][d], +1 pad
    __shared__ float ttr[64][65];   // [d][t], +1 pad
    const int tid = threadIdx.x;
    const int d0 = blockIdx.x * 64, t0 = blockIdx.y * 64, b = blockIdx.z;
    const int cl = tid & 63, q = tid >> 6;

    for (int r = q; r < 67; r += 4) {
        const int t = t0 - 3 + r;
        float v = 0.f;
        if (t >= 0) v = xz[((size_t)b * SEQ + t) * (2 * DI) + d0 + cl];
        tin[r][cl] = v;
    }
    __syncthreads();

    const float4 w = ((const float4*)cw)[d0 + cl];
    const float bb = cb[d0 + cl];
#pragma unroll
    for (int i = 0; i < 16; i++) {
        const int t = q * 16 + i;
        float a = bb;
        a = fmaf(tin[t + 0][cl], w.x, a);
        a = fmaf(tin[t + 1][cl], w.y, a);
        a = fmaf(tin[t + 2][cl], w.z, a);
        a = fmaf(tin[t + 3][cl], w.w, a);
        a = silu_fast(a);
        xc[((size_t)b * SEQ + t0 + t) * DI + d0 + cl] = a;   // coalesced in d
        ttr[cl][t] = a;
    }
    __syncthreads();
#pragma unroll
    for (int i = 0; i < 16; i++) {
        const int d = q * 16 + i;
        uT[((size_t)b * DI + d0 + d) * SEQ + t0 + cl] = ttr[d][cl];  // coalesced in t
    }
}

// Tiled transpose: in[row=b*SEQ+t, coloff+c] (ld ldin) -> out[(b*ncols+c)*SEQ + t]
__global__ __launch_bounds__(256) void trans_r2t(
    const float* __restrict__ in, int ldin, int coloff,
    float* __restrict__ out, int ncols)
{
    __shared__ float tile[64][65];
    const int tid = threadIdx.x;
    const int c0 = blockIdx.x * 64, t0 = blockIdx.y * 64, b = blockIdx.z;
    const int cl = tid & 63, q = tid >> 6;
#pragma unroll
    for (int i = 0; i < 16; i++) {
        const int r = q * 16 + i;
        tile[r][cl] = in[((size_t)b * SEQ + t0 + r) * ldin + coloff + c0 + cl];
    }
    __syncthreads();
#pragma unroll
    for (int i = 0; i < 16; i++) {
        const int cc = q * 16 + i;
        out[((size_t)b * ncols + c0 + cc) * SEQ + t0 + cl] = tile[cl][cc];
    }
}

// Tiled transpose back: in[(b*ncols+c)*SEQ + t] -> out[row=b*SEQ+t, c] (ld ldout)
__global__ __launch_bounds__(256) void trans_t2r(
    const float* __restrict__ in,
    float* __restrict__ out, int ldout, int ncols)
{
    __shared__ float tile[64][65];   // [t][d]
    const int tid = threadIdx.x;
    const int d0 = blockIdx.x * 64, t0 = blockIdx.y * 64, b = blockIdx.z;
    const int cl = tid & 63, q = tid >> 6;
#pragma unroll
    for (int i = 0; i < 16; i++) {
        const int d = q * 16 + i;
        tile[cl][d] = in[((size_t)b * ncols + d0 + d) * SEQ + t0 + cl];
    }
    __syncthreads();
#pragma unroll
    for (int i = 0; i < 16; i++) {
        const int t = q * 16 + i;
        out[((size_t)b * SEQ + t0 + t) * ldout + d0 + cl] = tile[t][cl];
    }
}

// ---------------- Chunked selective scan ----------------
// Phase 1: per (b,d,chunk) wave, lane = state n. float4 loads from transposed u/B.
__global__ __launch_bounds__(256) void scan_phase1(
    const float* __restrict__ dtrm,   // dt row-major at [row, d], ld 2*DI (in xz)
    const float* __restrict__ uT, const float* __restrict__ bcT,
    const float* __restrict__ A_log,
    float* __restrict__ hend, float* __restrict__ prodA)
{
    const int wid  = __builtin_amdgcn_readfirstlane(
                        (int)((blockIdx.x * 256 + threadIdx.x) >> 6));
    const int lane = threadIdx.x & 63;
    const int c  = wid & (NC - 1);
    const int bd = wid >> 3;
    const int b  = bd / DI;
    const int d  = bd - b * DI;

    const float An = -expf(A_log[d * DS + lane]) * LOG2E;
    const float* dtp = dtrm + ((size_t)b * SEQ + c * TCH) * (2 * DI) + d;
    const float* up  = uT  + (size_t)bd * SEQ + c * TCH;
    const float* Bp  = bcT + ((size_t)b * 128 + lane) * SEQ + c * TCH;

    float h = 0.f, sdt = 0.f;
    for (int t = 0; t < TCH; t += 4) {
        const float4 u4 = *(const float4*)(up + t);
        const float4 B4 = *(const float4*)(Bp + t);
        const float d0v = dtp[(size_t)(t + 0) * (2 * DI)];
        const float d1v = dtp[(size_t)(t + 1) * (2 * DI)];
        const float d2v = dtp[(size_t)(t + 2) * (2 * DI)];
        const float d3v = dtp[(size_t)(t + 3) * (2 * DI)];
        h = fmaf(exp2f(d0v * An), h, (d0v * u4.x) * B4.x); sdt += d0v;
        h = fmaf(exp2f(d1v * An), h, (d1v * u4.y) * B4.y); sdt += d1v;
        h = fmaf(exp2f(d2v * An), h, (d2v * u4.z) * B4.z); sdt += d2v;
        h = fmaf(exp2f(d3v * An), h, (d3v * u4.w) * B4.w); sdt += d3v;
    }
    hend [(size_t)wid * DS + lane] = h;
    prodA[(size_t)wid * DS + lane] = exp2f(An * sdt);
}

// Phase 2: per (b,d) wave, serial over chunks; writes h_in into prodA in place.
__global__ __launch_bounds__(256) void scan_phase2(
    float* __restrict__ hend, float* __restrict__ prodA)
{
    const int bd   = (blockIdx.x * 256 + threadIdx.x) >> 6;
    const int lane = threadIdx.x & 63;
    float h = 0.f;
#pragma unroll
    for (int c = 0; c < NC; c++) {
        const size_t off = ((size_t)bd * NC + c) * DS + lane;
        const float pA = prodA[off];
        const float he = hend[off];
        prodA[off] = h;
        h = fmaf(pA, h, he);
    }
}

// Phase 3: resumed scan, batched LDS reduce every 16 t, writes yT[b][d][t].
__global__ __launch_bounds__(256) void scan_phase3(
    const float* __restrict__ xzbase,  // dt at col d, z at col DI+d (ld 2*DI)
    const float* __restrict__ uT, const float* __restrict__ bcT,
    const float* __restrict__ A_log, const float* __restrict__ Dskip,
    const float* __restrict__ hin, float* __restrict__ yT)
{
    __shared__ float red[4][16 * 65];
    const int wid  = __builtin_amdgcn_readfirstlane(
                        (int)((blockIdx.x * 256 + threadIdx.x) >> 6));
    const int lane = threadIdx.x & 63;
    const int c  = wid & (NC - 1);
    const int bd = wid >> 3;
    const int b  = bd / DI;
    const int d  = bd - b * DI;

    const float An = -expf(A_log[d * DS + lane]) * LOG2E;
    const float Dd = Dskip[d];
    const float* dtp = xzbase + ((size_t)b * SEQ + c * TCH) * (2 * DI) + d;
    const float* zp  = dtp + DI;
    const float* up  = uT  + (size_t)bd * SEQ + c * TCH;
    const float* Bp  = bcT + ((size_t)b * 128 + lane) * SEQ + c * TCH;
    const float* Cp  = Bp + (size_t)64 * SEQ;
    float* yp = yT + (size_t)bd * SEQ + c * TCH;
    float* slab = &red[wid & 3][0];
    const int tt = lane & 15, seg = lane >> 4;

    float h = hin[(size_t)wid * DS + lane];
    for (int tb = 0; tb < TCH; tb += 16) {
        float p[16];
#pragma unroll
        for (int t4 = 0; t4 < 16; t4 += 4) {
            const int t = tb + t4;
            const float4 u4 = *(const float4*)(up + t);
            const float4 B4 = *(const float4*)(Bp + t);
            const float4 C4 = *(const float4*)(Cp + t);
            const float d0v = dtp[(size_t)(t + 0) * (2 * DI)];
            const float d1v = dtp[(size_t)(t + 1) * (2 * DI)];
            const float d2v = dtp[(size_t)(t + 2) * (2 * DI)];
            const float d3v = dtp[(size_t)(t + 3) * (2 * DI)];
            h = fmaf(exp2f(d0v * An), h, (d0v * u4.x) * B4.x); p[t4 + 0] = h * C4.x;
            h = fmaf(exp2f(d1v * An), h, (d1v * u4.y) * B4.y); p[t4 + 1] = h * C4.y;
            h = fmaf(exp2f(d2v * An), h, (d2v * u4.z) * B4.z); p[t4 + 2] = h * C4.z;
            h = fmaf(exp2f(d3v * An), h, (d3v * u4.w) * B4.w); p[t4 + 3] = h * C4.w;
        }
        // batched transpose-reduce over states (wave-synchronous LDS)
#pragma unroll
        for (int i = 0; i < 16; i++) slab[i * 65 + lane] = p[i];
        float s = 0.f;
#pragma unroll
        for (int j = 0; j < 16; j++) s += slab[tt * 65 + seg * 16 + j];
        s += __shfl_xor(s, 16, 64);
        s += __shfl_xor(s, 32, 64);
        // gating for timestep tb+tt (every lane computes; lanes 0..15 store)
        const float uvt = up[tb + tt];
        const float zvt = zp[(size_t)(tb + tt) * (2 * DI)];
        const float yv  = (s + Dd * uvt) * silu_fast(zvt);
        if (lane < 16) yp[tb + tt] = yv;
    }
}

extern "C" void kernel_launch(void* const* d_in, const int* in_sizes, int n_in,
                              void* d_out, int out_size, void* d_ws, size_t ws_size,
                              hipStream_t stream) {
    (void)in_sizes; (void)n_in; (void)out_size; (void)ws_size;
    const float* x    = (const float*)d_in[0];
    const float* Wi   = (const float*)d_in[1];
    const float* cw   = (const float*)d_in[2];
    const float* cb   = (const float*)d_in[3];
    const float* Wx   = (const float*)d_in[4];
    const float* Wdt  = (const float*)d_in[5];
    const float* bdt  = (const float*)d_in[6];
    const float* Alog = (const float*)d_in[7];
    const float* Dsk  = (const float*)d_in[8];
    const float* Wo   = (const float*)d_in[9];
    float* out = (float*)d_out;

    // Workspace (fp32), ~236 MB:
    float* xz    = (float*)d_ws;                          // [MROWS, 3072]
    float* xc    = xz    + (size_t)MROWS * (2 * DI);      // [MROWS, DI] u row-major; later yT [B*DI, SEQ] (same size)
    float* uT    = xc    + (size_t)MROWS * DI;            // [B*DI, SEQ]
    float* xdbl  = uT    + (size_t)MROWS * DI;            // [MROWS, 176]
    float* bcT   = xdbl  + (size_t)MROWS * XDC;           // [B*128, SEQ]
    float* xnext = bcT   + (size_t)BATCH * 128 * SEQ;     // [MROWS, 768]
    // hend/prodA alias xnext: disjoint lifetimes (scan runs strictly between
    // the consume of xnext (layer-2 GEMM 1) and the produce (layer-1 GEMM 6)).
    float* hend  = xnext;                                 // [B*DI*NC, DS]
    float* prodA = xnext + (size_t)BATCH * DI * NC * DS;  // [B*DI*NC, DS]

    const float* src = x;
    for (int i = 0; i < DEPTH; i++) {
        const float* Wi_l   = Wi   + (size_t)i * 2 * DI * DM;
        const float* cw_l   = cw   + (size_t)i * DI * DC;
        const float* cb_l   = cb   + (size_t)i * DI;
        const float* Wx_l   = Wx   + (size_t)i * XDC * DI;
        const float* Wdt_l  = Wdt  + (size_t)i * DI * DTR;
        const float* bdt_l  = bdt  + (size_t)i * DI;
        const float* Alog_l = Alog + (size_t)i * DI * DS;
        const float* Dsk_l  = Dsk  + (size_t)i * DI;
        const float* Wo_l   = Wo   + (size_t)i * DM * DI;
        float* dst = (i == DEPTH - 1) ? out : xnext;

        // 1. xz = src @ Wi^T                       [8192, 3072]
        gemm_nt<0><<<dim3(2 * DI / 128, MROWS / 128), 256, 0, stream>>>(
            src, DM, Wi_l, nullptr, xz, 2 * DI, 2 * DI, DM);
        // 2. u = silu(conv(xz[:, :DI])) -> xc (row-major) + uT (transposed)
        conv_silu_trans<<<dim3(DI / 64, SEQ / 64, BATCH), 256, 0, stream>>>(
            xz, cw_l, cb_l, xc, uT);
        // 3. xdbl = u @ Wx^T                       [8192, 176]
        gemm_nt<0><<<dim3((XDC + 127) / 128, MROWS / 128), 256, 0, stream>>>(
            xc, DI, Wx_l, nullptr, xdbl, XDC, XDC, DI);
        // 4. B/C transpose -> bcT [b][0:64=B,64:128=C][t]
        trans_r2t<<<dim3(2, SEQ / 64, BATCH), 256, 0, stream>>>(
            xdbl, XDC, DTR, bcT, 128);
        // 5. dt = softplus(xdbl[:, :48] @ Wdt^T + bdt) -> xz[:, 0:DI]
        gemm_nt<1><<<dim3(DI / 128, MROWS / 128), 256, 0, stream>>>(
            xdbl, XDC, Wdt_l, bdt_l, xz, 2 * DI, DI, DTR);
        // 6-8. chunked scan; yT written into xc region (u row-major is dead)
        scan_phase1<<<(BATCH * DI * NC) / 4, 256, 0, stream>>>(
            xz, uT, bcT, Alog_l, hend, prodA);
        scan_phase2<<<(BATCH * DI) / 4, 256, 0, stream>>>(hend, prodA);
        scan_phase3<<<(BATCH * DI * NC) / 4, 256, 0, stream>>>(
            xz, uT, bcT, Alog_l, Dsk_l, prodA, xc);
        // 9. y row-major -> xz[:, :DI] (dt dead, z untouched)
        trans_t2r<<<dim3(DI / 64, SEQ / 64, BATCH), 256, 0, stream>>>(
            xc, xz, 2 * DI, DI);
        // 10. dst = y @ Wo^T                       [8192, 768]
        gemm_nt<0><<<dim3(DM / 128, MROWS / 128), 256, 0, stream>>>(
            xz, 2 * DI, Wo_l, nullptr, dst, DM, DM, DI);

        src = dst;
    }
}

// Round 4
// 4788.134 us; speedup vs baseline: 1.2230x; 1.0854x over previous
//
#include <hip/hip_runtime.h>
#include <hip/hip_bf16.h>
#include <math.h>

// Problem constants (MambaStack reference)
#define DEPTH   2
#define DM      768      // d_model
#define DS      64       // d_state
#define DC      4        // d_conv
#define DI      1536     // d_inner
#define DTR     48       // dt_rank
#define BATCH   4
#define SEQ     2048
#define MROWS   (BATCH*SEQ)          // 8192
#define XDC     (DTR + 2*DS)         // 176 (xdbl cols)
#define NC      8                    // scan chunks
#define TCH     (SEQ/NC)             // 256 timesteps per chunk
#define LOG2E   1.44269504088896f

__device__ __forceinline__ float silu_fast(float x) {
    return x / (1.f + __expf(-x));
}
__device__ __forceinline__ float softplus_acc(float x) {
    return x > 20.f ? x : log1pf(expf(x));
}

// C[M,N] = A[M,K] (row-major, ldA) @ W[N,K]^T  (W row-major, ld = K)
// EPI: 0 = none, 1 = softplus(x + bias[col])
template<int EPI>
__global__ __launch_bounds__(256, 2) void gemm_nt(
    const float* __restrict__ A, int ldA,
    const float* __restrict__ W,
    const float* __restrict__ bias,
    float* __restrict__ C, int ldC,
    int N, int K)
{
    __shared__ float As[8][132];
    __shared__ float Bs[8][132];
    const int tid = threadIdx.x;
    const int bm0 = blockIdx.y * 128;
    const int bn0 = blockIdx.x * 128;
    const int tx = tid & 15;
    const int ty = tid >> 4;
    const int lrow = tid >> 1;
    const int lk4  = (tid & 1) * 4;

    float acc[8][8];
#pragma unroll
    for (int i = 0; i < 8; i++)
#pragma unroll
        for (int j = 0; j < 8; j++) acc[i][j] = 0.f;

    for (int k0 = 0; k0 < K; k0 += 8) {
        const float4 av = *(const float4*)(A + (size_t)(bm0 + lrow) * ldA + (k0 + lk4));
        float4 wv;
        const int wrow = bn0 + lrow;
        if (wrow < N) wv = *(const float4*)(W + (size_t)wrow * K + (k0 + lk4));
        else          wv = make_float4(0.f, 0.f, 0.f, 0.f);
        __syncthreads();
        As[lk4 + 0][lrow] = av.x; As[lk4 + 1][lrow] = av.y;
        As[lk4 + 2][lrow] = av.z; As[lk4 + 3][lrow] = av.w;
        Bs[lk4 + 0][lrow] = wv.x; Bs[lk4 + 1][lrow] = wv.y;
        Bs[lk4 + 2][lrow] = wv.z; Bs[lk4 + 3][lrow] = wv.w;
        __syncthreads();
#pragma unroll
        for (int kk = 0; kk < 8; kk++) {
            const float4 a0 = *(const float4*)&As[kk][ty * 8];
            const float4 a1 = *(const float4*)&As[kk][ty * 8 + 4];
            const float4 b0 = *(const float4*)&Bs[kk][tx * 8];
            const float4 b1 = *(const float4*)&Bs[kk][tx * 8 + 4];
            const float ar[8] = {a0.x, a0.y, a0.z, a0.w, a1.x, a1.y, a1.z, a1.w};
            const float br[8] = {b0.x, b0.y, b0.z, b0.w, b1.x, b1.y, b1.z, b1.w};
#pragma unroll
            for (int i = 0; i < 8; i++)
#pragma unroll
                for (int j = 0; j < 8; j++)
                    acc[i][j] = fmaf(ar[i], br[j], acc[i][j]);
        }
    }

#pragma unroll
    for (int i = 0; i < 8; i++) {
        const int row = bm0 + ty * 8 + i;
#pragma unroll
        for (int j4 = 0; j4 < 8; j4 += 4) {
            const int col = bn0 + tx * 8 + j4;
            if (col + 3 < N) {
                float4 v = make_float4(acc[i][j4], acc[i][j4 + 1], acc[i][j4 + 2], acc[i][j4 + 3]);
                if (EPI == 1) {
                    v.x = softplus_acc(v.x + bias[col + 0]);
                    v.y = softplus_acc(v.y + bias[col + 1]);
                    v.z = softplus_acc(v.z + bias[col + 2]);
                    v.w = softplus_acc(v.w + bias[col + 3]);
                }
                *(float4*)(C + (size_t)row * ldC + col) = v;
            }
        }
    }
}

// C[M,N] = A @ W^T where A is given K-MAJOR per batch: AT[(b*K + k)*SEQ + t],
// m = b*SEQ + t (SEQ multiple of 128 so a 128-row m-tile stays within one b).
// No LDS transpose needed on the A side (AT is already [k][m]).
__global__ __launch_bounds__(256, 2) void gemm_tn(
    const float* __restrict__ AT,
    const float* __restrict__ W,
    float* __restrict__ C, int ldC,
    int N, int K)
{
    __shared__ float As[8][132];
    __shared__ float Bs[8][132];
    const int tid = threadIdx.x;
    const int bm0 = blockIdx.y * 128;
    const int bn0 = blockIdx.x * 128;
    const int bb  = bm0 / SEQ;
    const int t0  = bm0 - bb * SEQ;
    const int tx = tid & 15;
    const int ty = tid >> 4;
    const int arow = tid >> 5;          // k row 0..7
    const int am4  = (tid & 31) * 4;    // m offset 0..124
    const int lrow = tid >> 1;
    const int lk4  = (tid & 1) * 4;

    float acc[8][8];
#pragma unroll
    for (int i = 0; i < 8; i++)
#pragma unroll
        for (int j = 0; j < 8; j++) acc[i][j] = 0.f;

    for (int k0 = 0; k0 < K; k0 += 8) {
        const float4 av = *(const float4*)(AT + ((size_t)(bb * K + k0 + arow)) * SEQ + t0 + am4);
        float4 wv;
        const int wrow = bn0 + lrow;
        if (wrow < N) wv = *(const float4*)(W + (size_t)wrow * K + (k0 + lk4));
        else          wv = make_float4(0.f, 0.f, 0.f, 0.f);
        __syncthreads();
        *(float4*)&As[arow][am4] = av;
        Bs[lk4 + 0][lrow] = wv.x; Bs[lk4 + 1][lrow] = wv.y;
        Bs[lk4 + 2][lrow] = wv.z; Bs[lk4 + 3][lrow] = wv.w;
        __syncthreads();
#pragma unroll
        for (int kk = 0; kk < 8; kk++) {
            const float4 a0 = *(const float4*)&As[kk][ty * 8];
            const float4 a1 = *(const float4*)&As[kk][ty * 8 + 4];
            const float4 b0 = *(const float4*)&Bs[kk][tx * 8];
            const float4 b1 = *(const float4*)&Bs[kk][tx * 8 + 4];
            const float ar[8] = {a0.x, a0.y, a0.z, a0.w, a1.x, a1.y, a1.z, a1.w};
            const float br[8] = {b0.x, b0.y, b0.z, b0.w, b1.x, b1.y, b1.z, b1.w};
#pragma unroll
            for (int i = 0; i < 8; i++)
#pragma unroll
                for (int j = 0; j < 8; j++)
                    acc[i][j] = fmaf(ar[i], br[j], acc[i][j]);
        }
    }

#pragma unroll
    for (int i = 0; i < 8; i++) {
        const int row = bm0 + ty * 8 + i;
#pragma unroll
        for (int j4 = 0; j4 < 8; j4 += 4) {
            const int col = bn0 + tx * 8 + j4;
            if (col + 3 < N) {
                *(float4*)(C + (size_t)row * ldC + col) =
                    make_float4(acc[i][j4], acc[i][j4 + 1], acc[i][j4 + 2], acc[i][j4 + 3]);
            }
        }
    }
}

// Depthwise causal conv (K=4) + SiLU -> uT [b][d][t] only.
__global__ __launch_bounds__(256) void conv_silu_T(
    const float* __restrict__ xz, const float* __restrict__ cw,
    const float* __restrict__ cb, float* __restrict__ uT)
{
    __shared__ float tin[67][65];   // [t(-3..63)][d], +1 pad
    __shared__ float ttr[64][65];   // [d][t], +1 pad
    const int tid = threadIdx.x;
    const int d0 = blockIdx.x * 64, t0 = blockIdx.y * 64, b = blockIdx.z;
    const int cl = tid & 63, q = tid >> 6;

    for (int r = q; r < 67; r += 4) {
        const int t = t0 - 3 + r;
        float v = 0.f;
        if (t >= 0) v = xz[((size_t)b * SEQ + t) * (2 * DI) + d0 + cl];
        tin[r][cl] = v;
    }
    __syncthreads();

    const float4 w = ((const float4*)cw)[d0 + cl];
    const float bb = cb[d0 + cl];
#pragma unroll
    for (int i = 0; i < 16; i++) {
        const int t = q * 16 + i;
        float a = bb;
        a = fmaf(tin[t + 0][cl], w.x, a);
        a = fmaf(tin[t + 1][cl], w.y, a);
        a = fmaf(tin[t + 2][cl], w.z, a);
        a = fmaf(tin[t + 3][cl], w.w, a);
        ttr[cl][t] = silu_fast(a);
    }
    __syncthreads();
#pragma unroll
    for (int i = 0; i < 16; i++) {
        const int d = q * 16 + i;
        uT[((size_t)b * DI + d0 + d) * SEQ + t0 + cl] = ttr[d][cl];  // coalesced in t
    }
}

// Tiled transpose: in[row=b*SEQ+t, coloff+c] (ld ldin) -> out[(b*ncols+c)*SEQ + t]
__global__ __launch_bounds__(256) void trans_r2t(
    const float* __restrict__ in, int ldin, int coloff,
    float* __restrict__ out, int ncols)
{
    __shared__ float tile[64][65];
    const int tid = threadIdx.x;
    const int c0 = blockIdx.x * 64, t0 = blockIdx.y * 64, b = blockIdx.z;
    const int cl = tid & 63, q = tid >> 6;
#pragma unroll
    for (int i = 0; i < 16; i++) {
        const int r = q * 16 + i;
        tile[r][cl] = in[((size_t)b * SEQ + t0 + r) * ldin + coloff + c0 + cl];
    }
    __syncthreads();
#pragma unroll
    for (int i = 0; i < 16; i++) {
        const int cc = q * 16 + i;
        out[((size_t)b * ncols + c0 + cc) * SEQ + t0 + cl] = tile[cl][cc];
    }
}

// ---------------- Chunked selective scan ----------------
// dtT/uT are [b][d][t]: wave-uniform addresses -> scalar (SMEM) float4 loads.
// Only B/C (lane = state n) are per-lane vector loads.

// Phase 1: per (b,d,chunk) wave; computes chunk-local h_end and decay product.
__global__ __launch_bounds__(256, 4) void scan_phase1(
    const float* __restrict__ dtT, const float* __restrict__ uT,
    const float* __restrict__ bcT, const float* __restrict__ A_log,
    float* __restrict__ hend, float* __restrict__ prodA)
{
    const int wid  = __builtin_amdgcn_readfirstlane(
                        (int)((blockIdx.x * 256 + threadIdx.x) >> 6));
    const int lane = threadIdx.x & 63;
    const int c  = wid & (NC - 1);
    const int bd = wid >> 3;
    const int b  = bd / DI;
    const int d  = bd - b * DI;

    const float An = -expf(A_log[d * DS + lane]) * LOG2E;
    const float* dtp = dtT + (size_t)bd * SEQ + c * TCH;   // wave-uniform
    const float* up  = uT  + (size_t)bd * SEQ + c * TCH;   // wave-uniform
    const float* Bp  = bcT + ((size_t)b * 128 + lane) * SEQ + c * TCH;

    float h = 0.f, sdt = 0.f;
    for (int tb = 0; tb < TCH; tb += 16) {
        float4 dt4[4], u4[4], B4[4];
#pragma unroll
        for (int g = 0; g < 4; g++) {
            dt4[g] = *(const float4*)(dtp + tb + 4 * g);
            u4[g]  = *(const float4*)(up  + tb + 4 * g);
            B4[g]  = *(const float4*)(Bp  + tb + 4 * g);
        }
#pragma unroll
        for (int g = 0; g < 4; g++) {
            h = fmaf(exp2f(dt4[g].x * An), h, (dt4[g].x * u4[g].x) * B4[g].x); sdt += dt4[g].x;
            h = fmaf(exp2f(dt4[g].y * An), h, (dt4[g].y * u4[g].y) * B4[g].y); sdt += dt4[g].y;
            h = fmaf(exp2f(dt4[g].z * An), h, (dt4[g].z * u4[g].z) * B4[g].z); sdt += dt4[g].z;
            h = fmaf(exp2f(dt4[g].w * An), h, (dt4[g].w * u4[g].w) * B4[g].w); sdt += dt4[g].w;
        }
    }
    hend [(size_t)wid * DS + lane] = h;
    prodA[(size_t)wid * DS + lane] = exp2f(An * sdt);
}

// Phase 2: per (b,d) wave, serial over chunks; writes h_in into prodA in place.
__global__ __launch_bounds__(256) void scan_phase2(
    float* __restrict__ hend, float* __restrict__ prodA)
{
    const int bd   = (blockIdx.x * 256 + threadIdx.x) >> 6;
    const int lane = threadIdx.x & 63;
    float h = 0.f;
#pragma unroll
    for (int c = 0; c < NC; c++) {
        const size_t off = ((size_t)bd * NC + c) * DS + lane;
        const float pA = prodA[off];
        const float he = hend[off];
        prodA[off] = h;
        h = fmaf(pA, h, he);
    }
}

// Phase 3: resumed scan, batched LDS reduce every 16 t, gated y written
// row-major into xz[:, 0:DI] (dt row-major region there is dead; z at DI+d).
__global__ __launch_bounds__(256, 4) void scan_phase3(
    const float* __restrict__ dtT, const float* __restrict__ uT,
    const float* __restrict__ bcT, const float* __restrict__ A_log,
    const float* __restrict__ Dskip, const float* __restrict__ hin,
    float* __restrict__ xz)
{
    __shared__ float red[4][16 * 65];
    const int wid  = __builtin_amdgcn_readfirstlane(
                        (int)((blockIdx.x * 256 + threadIdx.x) >> 6));
    const int lane = threadIdx.x & 63;
    const int c  = wid & (NC - 1);
    const int bd = wid >> 3;
    const int b  = bd / DI;
    const int d  = bd - b * DI;

    const float An = -expf(A_log[d * DS + lane]) * LOG2E;
    const float Dd = Dskip[d];
    const float* dtp = dtT + (size_t)bd * SEQ + c * TCH;   // wave-uniform
    const float* up  = uT  + (size_t)bd * SEQ + c * TCH;   // wave-uniform
    const float* Bp  = bcT + ((size_t)b * 128 + lane) * SEQ + c * TCH;
    const float* Cp  = Bp + (size_t)64 * SEQ;
    float* xzc = xz + ((size_t)b * SEQ + c * TCH) * (2 * DI) + d;  // y col d, z col DI+d
    float* slab = &red[threadIdx.x >> 6][0];
    const int tt = lane & 15, seg = lane >> 4;

    float h = hin[(size_t)wid * DS + lane];
    for (int tb = 0; tb < TCH; tb += 16) {
        float4 dt4[4], u4[4], B4[4], C4[4];
#pragma unroll
        for (int g = 0; g < 4; g++) {
            dt4[g] = *(const float4*)(dtp + tb + 4 * g);
            u4[g]  = *(const float4*)(up  + tb + 4 * g);
            B4[g]  = *(const float4*)(Bp  + tb + 4 * g);
            C4[g]  = *(const float4*)(Cp  + tb + 4 * g);
        }
        float p[16];
#pragma unroll
        for (int g = 0; g < 4; g++) {
            h = fmaf(exp2f(dt4[g].x * An), h, (dt4[g].x * u4[g].x) * B4[g].x); p[4*g+0] = h * C4[g].x;
            h = fmaf(exp2f(dt4[g].y * An), h, (dt4[g].y * u4[g].y) * B4[g].y); p[4*g+1] = h * C4[g].y;
            h = fmaf(exp2f(dt4[g].z * An), h, (dt4[g].z * u4[g].z) * B4[g].z); p[4*g+2] = h * C4[g].z;
            h = fmaf(exp2f(dt4[g].w * An), h, (dt4[g].w * u4[g].w) * B4[g].w); p[4*g+3] = h * C4[g].w;
        }
        // wave-synchronous LDS transpose-reduce over the 64 states
#pragma unroll
        for (int i = 0; i < 16; i++) slab[i * 65 + lane] = p[i];
        float s = 0.f;
#pragma unroll
        for (int j = 0; j < 16; j++) s += slab[tt * 65 + seg * 16 + j];
        s += __shfl_xor(s, 16, 64);
        s += __shfl_xor(s, 32, 64);
        // gating for timestep tb+tt
        const float uvt = up[tb + tt];
        const float zvt = xzc[(size_t)(tb + tt) * (2 * DI) + DI];
        const float yv  = (s + Dd * uvt) * silu_fast(zvt);
        if (lane < 16) xzc[(size_t)(tb + tt) * (2 * DI)] = yv;
    }
}

extern "C" void kernel_launch(void* const* d_in, const int* in_sizes, int n_in,
                              void* d_out, int out_size, void* d_ws, size_t ws_size,
                              hipStream_t stream) {
    (void)in_sizes; (void)n_in; (void)out_size; (void)ws_size;
    const float* x    = (const float*)d_in[0];
    const float* Wi   = (const float*)d_in[1];
    const float* cw   = (const float*)d_in[2];
    const float* cb   = (const float*)d_in[3];
    const float* Wx   = (const float*)d_in[4];
    const float* Wdt  = (const float*)d_in[5];
    const float* bdt  = (const float*)d_in[6];
    const float* Alog = (const float*)d_in[7];
    const float* Dsk  = (const float*)d_in[8];
    const float* Wo   = (const float*)d_in[9];
    float* out = (float*)d_out;

    // Workspace (fp32), ~236 MB (same footprint as round 3; dtT replaces xc):
    float* xz    = (float*)d_ws;                          // [MROWS, 3072]
    float* uT    = xz    + (size_t)MROWS * (2 * DI);      // [B*DI, SEQ]
    float* dtT   = uT    + (size_t)MROWS * DI;            // [B*DI, SEQ]
    float* xdbl  = dtT   + (size_t)MROWS * DI;            // [MROWS, 176]
    float* bcT   = xdbl  + (size_t)MROWS * XDC;           // [B*128, SEQ]
    float* xnext = bcT   + (size_t)BATCH * 128 * SEQ;     // [MROWS, 768]
    // hend/prodA alias xnext: disjoint lifetimes (scan runs strictly between
    // the consume of xnext (layer-2 GEMM 1) and the produce (layer-1 GEMM 6)).
    float* hend  = xnext;                                 // [B*DI*NC, DS]
    float* prodA = xnext + (size_t)BATCH * DI * NC * DS;  // [B*DI*NC, DS]

    const float* src = x;
    for (int i = 0; i < DEPTH; i++) {
        const float* Wi_l   = Wi   + (size_t)i * 2 * DI * DM;
        const float* cw_l   = cw   + (size_t)i * DI * DC;
        const float* cb_l   = cb   + (size_t)i * DI;
        const float* Wx_l   = Wx   + (size_t)i * XDC * DI;
        const float* Wdt_l  = Wdt  + (size_t)i * DI * DTR;
        const float* bdt_l  = bdt  + (size_t)i * DI;
        const float* Alog_l = Alog + (size_t)i * DI * DS;
        const float* Dsk_l  = Dsk  + (size_t)i * DI;
        const float* Wo_l   = Wo   + (size_t)i * DM * DI;
        float* dst = (i == DEPTH - 1) ? out : xnext;

        // 1. xz = src @ Wi^T                       [8192, 3072]
        gemm_nt<0><<<dim3(2 * DI / 128, MROWS / 128), 256, 0, stream>>>(
            src, DM, Wi_l, nullptr, xz, 2 * DI, 2 * DI, DM);
        // 2. uT = silu(conv(xz[:, :DI])) transposed [b][d][t]
        conv_silu_T<<<dim3(DI / 64, SEQ / 64, BATCH), 256, 0, stream>>>(
            xz, cw_l, cb_l, uT);
        // 3. xdbl = u @ Wx^T via k-major uT        [8192, 176]
        gemm_tn<<<dim3((XDC + 127) / 128, MROWS / 128), 256, 0, stream>>>(
            uT, Wx_l, xdbl, XDC, XDC, DI);
        // 4. B/C transpose -> bcT [b][0:64=B,64:128=C][t]
        trans_r2t<<<dim3(2, SEQ / 64, BATCH), 256, 0, stream>>>(
            xdbl, XDC, DTR, bcT, 128);
        // 5. dt = softplus(xdbl[:, :48] @ Wdt^T + bdt) -> xz[:, 0:DI] (x-half dead)
        gemm_nt<1><<<dim3(DI / 128, MROWS / 128), 256, 0, stream>>>(
            xdbl, XDC, Wdt_l, bdt_l, xz, 2 * DI, DI, DTR);
        // 6. dt transpose -> dtT [b][d][t]
        trans_r2t<<<dim3(DI / 64, SEQ / 64, BATCH), 256, 0, stream>>>(
            xz, 2 * DI, 0, dtT, DI);
        // 7-9. chunked scan; gated y overwrites xz[:, :DI] row-major
        scan_phase1<<<(BATCH * DI * NC) / 4, 256, 0, stream>>>(
            dtT, uT, bcT, Alog_l, hend, prodA);
        scan_phase2<<<(BATCH * DI) / 4, 256, 0, stream>>>(hend, prodA);
        scan_phase3<<<(BATCH * DI * NC) / 4, 256, 0, stream>>>(
            dtT, uT, bcT, Alog_l, Dsk_l, prodA, xz);
        // 10. dst = y @ Wo^T                       [8192, 768]
        gemm_nt<0><<<dim3(DM / 128, MROWS / 128), 256, 0, stream>>>(
            xz, 2 * DI, Wo_l, nullptr, dst, DM, DM, DI);

        src = dst;
    }
}